// Round 3
// baseline (371.682 us; speedup 1.0000x reference)
//
#include <hip/hip_runtime.h>

typedef _Float16 f16x8 __attribute__((ext_vector_type(8)));
typedef _Float16 f16x4 __attribute__((ext_vector_type(4)));
typedef float f32x4 __attribute__((ext_vector_type(4)));

// Async global->LDS, 16B per lane. LDS dest must be wave-uniform base; HW adds lane*16.
__device__ __forceinline__ void lds_load16(const _Float16* g, _Float16* l) {
    __builtin_amdgcn_global_load_lds(
        (const __attribute__((address_space(1))) void*)g,
        (__attribute__((address_space(3))) void*)l,
        16, 0, 0);
}

// ---------------------------------------------------------------------------
// NT GEMM: C[M,N] = A[M,K] * B[N,K]^T, f16 in, fp32 acc, 128x128 tile, BK=32,
// 256 thr (4 waves, 2x2 of 64x64), mfma_f32_16x16x32_f16, global_load_lds.
// MODE 1: dual GEMM (z selects {A,B,bias,C} vs {A2,B2,bias2,C2}), +bias[n], f16 out
// MODE 2: +bias[m], f16 out
// MODE 3: S-epilogue — store exp(acc*alpha) f16, atomic f32 row sums
// MODE 4: PV split-K2 — z = batch*2+kchunk, atomicAdd f32 out scaled by
//         1/rowsum[row]
// ---------------------------------------------------------------------------
template <int MODE>
__global__ __launch_bounds__(256, 2)
void gemm_nt(const _Float16* A, const _Float16* B, void* Cv, const float* bias,
             const _Float16* A2, const _Float16* B2, const float* bias2, void* C2,
             float* rowsum,
             int M, int N, int K, int lda, int ldb, int ldc,
             long long strideA, long long strideB, long long strideC, float alpha)
{
    const int z = blockIdx.z;
    size_t cbase = 0;
    if (MODE == 1) {
        if (z) { A = A2; B = B2; bias = bias2; Cv = C2; }   // <-- B2 swap was missing
    } else if (MODE == 3) {
        A += (size_t)z * strideA;
        B += (size_t)z * strideB;
        cbase = (size_t)z * strideC;
        rowsum += (size_t)z * M;
    } else if (MODE == 4) {
        const int b = z >> 1, kc = z & 1;
        A += (size_t)b * strideA + (size_t)kc * 1024;   // lda = 2048, half-split cols
        B += (size_t)b * 2048 + (size_t)kc * 1024;      // vT col offset, ldb = 8192
        cbase = (size_t)b * strideC;
        rowsum += (size_t)b * M;
    }

    const int m0 = blockIdx.y * 128;
    const int n0 = blockIdx.x * 128;

    __shared__ __align__(16) _Float16 As[128 * 32];
    __shared__ __align__(16) _Float16 Bs[128 * 32];

    const int t    = threadIdx.x;
    const int w    = t >> 6;
    const int lane = t & 63;
    const int ln   = lane & 15;
    const int kq   = lane >> 4;
    const int wm   = (w & 1) * 64;
    const int wn   = (w >> 1) * 64;

    // Staging: 128 rows x 64B. 512 x 16B chunks, 2 per thread, LDS contiguous.
    const int arow = t >> 2;
    const int kcf  = (t & 3) * 8;
    const _Float16* gA0 = A + (size_t)(m0 + arow) * lda + kcf;
    const _Float16* gA1 = A + (size_t)(m0 + 64 + arow) * lda + kcf;
    const _Float16* gB0 = B + (size_t)(n0 + arow) * ldb + kcf;
    const _Float16* gB1 = B + (size_t)(n0 + 64 + arow) * ldb + kcf;
    _Float16* lA0 = As + w * 512;
    _Float16* lA1 = As + 2048 + w * 512;
    _Float16* lB0 = Bs + w * 512;
    _Float16* lB1 = Bs + 2048 + w * 512;

    f32x4 acc[4][4] = {};

    for (int k0 = 0; k0 < K; k0 += 32) {
        __syncthreads();
        lds_load16(gA0 + k0, lA0);
        lds_load16(gA1 + k0, lA1);
        lds_load16(gB0 + k0, lB0);
        lds_load16(gB1 + k0, lB1);
        __syncthreads();

        f16x8 af[4], bf[4];
#pragma unroll
        for (int i = 0; i < 4; ++i)
            af[i] = *(const f16x8*)(As + (wm + i * 16 + ln) * 32 + kq * 8);
#pragma unroll
        for (int i = 0; i < 4; ++i)
            bf[i] = *(const f16x8*)(Bs + (wn + i * 16 + ln) * 32 + kq * 8);
#pragma unroll
        for (int i = 0; i < 4; ++i)
#pragma unroll
            for (int j = 0; j < 4; ++j)
                acc[i][j] = __builtin_amdgcn_mfma_f32_16x16x32_f16(af[i], bf[j], acc[i][j], 0, 0, 0);
    }

    // Epilogue. C/D layout: col = lane&15, row = (lane>>4)*4 + reg.
    float*    Cf = (float*)Cv;
    _Float16* Ch = (_Float16*)Cv;
#pragma unroll
    for (int i = 0; i < 4; ++i) {
        const int rbase = m0 + wm + i * 16 + kq * 4;

        if (MODE == 1 || MODE == 2) {
#pragma unroll
            for (int j = 0; j < 4; ++j) {
                const int gcol = n0 + wn + j * 16 + ln;
#pragma unroll
                for (int r = 0; r < 4; ++r) {
                    float vv = acc[i][j][r];
                    if (MODE == 1) vv += bias[gcol];
                    if (MODE == 2) vv += bias[rbase + r];
                    Ch[cbase + (size_t)(rbase + r) * ldc + gcol] = (_Float16)vv;
                }
            }
        } else if (MODE == 3) {
            float rs[4] = {0.f, 0.f, 0.f, 0.f};
#pragma unroll
            for (int j = 0; j < 4; ++j) {
                const int gcol = n0 + wn + j * 16 + ln;
#pragma unroll
                for (int r = 0; r < 4; ++r) {
                    float e = __expf(acc[i][j][r] * alpha);
                    Ch[cbase + (size_t)(rbase + r) * ldc + gcol] = (_Float16)e;
                    rs[r] += e;
                }
            }
#pragma unroll
            for (int r = 0; r < 4; ++r) {
                float s = rs[r];
                s += __shfl_xor(s, 1);
                s += __shfl_xor(s, 2);
                s += __shfl_xor(s, 4);
                s += __shfl_xor(s, 8);
                if (ln == 0) atomicAdd(&rowsum[rbase + r], s);
            }
        } else if (MODE == 4) {
            float inv[4];
#pragma unroll
            for (int r = 0; r < 4; ++r) inv[r] = 1.f / rowsum[rbase + r];
#pragma unroll
            for (int j = 0; j < 4; ++j) {
                const int gcol = n0 + wn + j * 16 + ln;
#pragma unroll
                for (int r = 0; r < 4; ++r)
                    atomicAdd(&Cf[cbase + (size_t)(rbase + r) * ldc + gcol],
                              acc[i][j][r] * inv[r]);
            }
        }
    }
}

// ---------------------------------------------------------------------------
// Merged f32->f16 convert for the 3 inputs (grid.y selects), plus:
//   y==0, x<32 : zero rowsum[8192]
//   y==1       : zero d_out (8.4M f32) for PV's atomic accumulation
// ---------------------------------------------------------------------------
__global__ __launch_bounds__(256)
void cvt_and_zero(const float4* __restrict__ x0, _Float16* __restrict__ y0,
                  const float4* __restrict__ x1, _Float16* __restrict__ y1,
                  const float4* __restrict__ x2, _Float16* __restrict__ y2,
                  float* __restrict__ rowsum, float4* __restrict__ outz)
{
    const size_t i = (size_t)blockIdx.x * 256 + threadIdx.x;
    const float4* x = blockIdx.y == 0 ? x0 : blockIdx.y == 1 ? x1 : x2;
    _Float16*    yy = blockIdx.y == 0 ? y0 : blockIdx.y == 1 ? y1 : y2;
    float4 f = x[i];
    f16x4 o = { (_Float16)f.x, (_Float16)f.y, (_Float16)f.z, (_Float16)f.w };
    *(f16x4*)(yy + i * 4) = o;
    if (blockIdx.y == 0 && blockIdx.x < 32)
        rowsum[blockIdx.x * 256 + threadIdx.x] = 0.f;
    if (blockIdx.y == 1)
        outz[i] = make_float4(0.f, 0.f, 0.f, 0.f);
}

// ---------------------------------------------------------------------------
// Merged 1024x1024 f32 -> f16 transpose x3 (grid.z selects W).
// ---------------------------------------------------------------------------
__global__ __launch_bounds__(256)
void transpose_w_1024(const float* __restrict__ W0, _Float16* __restrict__ T0,
                      const float* __restrict__ W1, _Float16* __restrict__ T1,
                      const float* __restrict__ W2, _Float16* __restrict__ T2)
{
    const float* W = blockIdx.z == 0 ? W0 : blockIdx.z == 1 ? W1 : W2;
    _Float16*   WT = blockIdx.z == 0 ? T0 : blockIdx.z == 1 ? T1 : T2;
    __shared__ float tile[32][33];
    const int bx = blockIdx.x * 32;
    const int by = blockIdx.y * 32;
    const int tx = threadIdx.x;
    const int ty = threadIdx.y;
#pragma unroll
    for (int i = ty; i < 32; i += 8)
        tile[i][tx] = W[(size_t)(by + i) * 1024 + bx + tx];
    __syncthreads();
#pragma unroll
    for (int i = ty; i < 32; i += 8)
        WT[(size_t)(bx + i) * 1024 + by + tx] = (_Float16)tile[tx][i];
}

// ---------------------------------------------------------------------------
// B=4, Lq=Lk=2048, D=1024.
// q,k proj (dual launch) ; vT proj ; S~ = exp(q k^T / 32) + rowsums (fused) ;
// out = S~ @ v / rowsum (split-K2, atomic f32).
// ---------------------------------------------------------------------------
extern "C" void kernel_launch(void* const* d_in, const int* in_sizes, int n_in,
                              void* d_out, int out_size, void* d_ws, size_t ws_size,
                              hipStream_t stream)
{
    const float* Xq = (const float*)d_in[0];
    const float* Xk = (const float*)d_in[1];
    const float* Xv = (const float*)d_in[2];
    const float* Wq = (const float*)d_in[3];
    const float* bq = (const float*)d_in[4];
    const float* Wk = (const float*)d_in[5];
    const float* bk = (const float*)d_in[6];
    const float* Wv = (const float*)d_in[7];
    const float* bv = (const float*)d_in[8];
    float* out = (float*)d_out;

    const size_t XN = (size_t)8192 * 1024;
    const size_t WN = (size_t)1024 * 1024;

    _Float16* ws  = (_Float16*)d_ws;
    _Float16* Xqh = ws;
    _Float16* Xkh = Xqh + XN;
    _Float16* Xvh = Xkh + XN;
    _Float16* WqT = Xvh + XN;
    _Float16* WkT = WqT + WN;
    _Float16* WvT = WkT + WN;
    _Float16* qh  = WvT + WN;
    _Float16* kh  = qh + XN;
    _Float16* vT  = kh + XN;                     // [1024 x 8192]
    _Float16* S   = vT + XN;                     // [4 x 2048 x 2048] (holds exp)
    float* rowsum = (float*)(S + (size_t)4 * 2048 * 2048);   // [8192]

    // 1. convert inputs to f16 + zero rowsum + zero d_out
    {
        dim3 g(8192, 3);
        cvt_and_zero<<<g, 256, 0, stream>>>((const float4*)Xq, Xqh,
                                            (const float4*)Xk, Xkh,
                                            (const float4*)Xv, Xvh,
                                            rowsum, (float4*)out);
    }

    // 2. transpose weights to f16 W^T (one launch, z=3)
    {
        dim3 tb(32, 8), tg(32, 32, 3);
        transpose_w_1024<<<tg, tb, 0, stream>>>(Wq, WqT, Wk, WkT, Wv, WvT);
    }

    // 3a. q & k projections, dual launch: C[8192,1024], 1024 blocks
    {
        dim3 g(8, 64, 2);
        gemm_nt<1><<<g, 256, 0, stream>>>(Xqh, WqT, qh, bq,
            Xkh, WkT, bk, kh, nullptr,
            8192, 1024, 1024, 1024, 1024, 1024, 0, 0, 0, 1.f);
    }
    // 3b. vT[d][l] = sum_k WvT[d][k] Xv[l][k] + bv[d]
    {
        dim3 g(64, 8, 1);
        gemm_nt<2><<<g, 256, 0, stream>>>(WvT, Xvh, vT, bv,
            nullptr, nullptr, nullptr, nullptr, nullptr,
            1024, 8192, 1024, 1024, 1024, 8192, 0, 0, 0, 1.f);
    }

    // 4. S~ = exp(q k^T / 32), f16, + f32 row sums (atomic)
    {
        dim3 g(16, 16, 4);
        gemm_nt<3><<<g, 256, 0, stream>>>(qh, kh, S, nullptr,
            nullptr, nullptr, nullptr, nullptr, rowsum,
            2048, 2048, 1024, 1024, 1024, 2048,
            (long long)2048 * 1024, (long long)2048 * 1024, (long long)2048 * 2048,
            0.03125f);
    }

    // 5. out += S~ @ v / rowsum  (split-K2: z = batch*2 + kchunk, atomic f32)
    {
        dim3 g(8, 16, 8);
        gemm_nt<4><<<g, 256, 0, stream>>>(S, vT, out, nullptr,
            nullptr, nullptr, nullptr, nullptr, rowsum,
            2048, 1024, 1024, 2048, 8192, 1024,
            (long long)2048 * 2048, 0, (long long)2048 * 1024,
            1.f);
    }
}

// Round 4
// 342.277 us; speedup vs baseline: 1.0859x; 1.0859x over previous
//
#include <hip/hip_runtime.h>

typedef _Float16 f16x8 __attribute__((ext_vector_type(8)));
typedef _Float16 f16x4 __attribute__((ext_vector_type(4)));
typedef float f32x4 __attribute__((ext_vector_type(4)));

// Async global->LDS, 16B per lane. LDS dest must be wave-uniform base; HW adds lane*16.
__device__ __forceinline__ void lds_load16(const _Float16* g, _Float16* l) {
    __builtin_amdgcn_global_load_lds(
        (const __attribute__((address_space(1))) void*)g,
        (__attribute__((address_space(3))) void*)l,
        16, 0, 0);
}

// ---------------------------------------------------------------------------
// NT GEMM core: C[M,N] = A[M,K]*B[N,K]^T. f16 in, fp32 acc, 128x128 tile,
// BK=32, 256 thr (4 waves, 2x2 of 64x64), mfma_f32_16x16x32_f16,
// global_load_lds width=16 staging. All shapes hardcoded per MODE.
//
// MODE 0: triple projection, z in {0,1,2}:
//   z=0: q  = Xq@WqT^T + bq[n]   C[8192,1024] f16, ldc=1024
//   z=1: k  = Xk@WkT^T + bk[n]   C[8192,1024] f16, ldc=1024
//   z=2: vT = WvT@Xv^T + bv[m]   C[1024,8192] f16, ldc=8192 (bx/by swapped)
// MODE 3: S~ = exp((q k^T)/32) f16 + atomic f32 row sums; z = batch
// MODE 5: out = (S~ @ v) * (1/rowsum[row]) f32 plain store; z = batch
// ---------------------------------------------------------------------------
template <int MODE>
__global__ __launch_bounds__(256, 2)
void gemm_core(const _Float16* A, const _Float16* B, void* Cv, const float* bias,
               const _Float16* Ax1, const _Float16* Bx1, void* Cx1, const float* bx1,
               const _Float16* Ax2, const _Float16* Bx2, void* Cx2, const float* bx2,
               float* rowsum)
{
    const int z = blockIdx.z;
    size_t cbase = 0;
    int lda, ldb, K, m0, n0;
    if (MODE == 0) {
        if (z == 1) { A = Ax1; B = Bx1; Cv = Cx1; bias = bx1; }
        else if (z == 2) { A = Ax2; B = Bx2; Cv = Cx2; bias = bx2; }
        lda = 1024; ldb = 1024; K = 1024;
        m0 = (z == 2 ? blockIdx.x : blockIdx.y) * 128;
        n0 = (z == 2 ? blockIdx.y : blockIdx.x) * 128;
    } else if (MODE == 3) {
        A += (size_t)z * 2048 * 1024;          // q slice
        B += (size_t)z * 2048 * 1024;          // k slice
        cbase = (size_t)z * 2048 * 2048;
        rowsum += z * 2048;
        lda = 1024; ldb = 1024; K = 1024;
        m0 = blockIdx.y * 128; n0 = blockIdx.x * 128;
    } else { // MODE 5
        A += (size_t)z * 2048 * 2048;          // S~ slice
        B += (size_t)z * 2048;                 // vT col offset (ldb 8192)
        cbase = (size_t)z * 2048 * 1024;
        rowsum += z * 2048;
        lda = 2048; ldb = 8192; K = 2048;
        m0 = blockIdx.y * 128; n0 = blockIdx.x * 128;
    }

    __shared__ __align__(16) _Float16 As[128 * 32];
    __shared__ __align__(16) _Float16 Bs[128 * 32];

    const int t    = threadIdx.x;
    const int w    = t >> 6;
    const int lane = t & 63;
    const int ln   = lane & 15;
    const int kq   = lane >> 4;
    const int wm   = (w & 1) * 64;
    const int wn   = (w >> 1) * 64;

    // Staging: 128 rows x 64B per operand. 512 x 16B chunks, 2/thread, LDS contiguous.
    const int arow = t >> 2;
    const int kcf  = (t & 3) * 8;
    const _Float16* gA0 = A + (size_t)(m0 + arow) * lda + kcf;
    const _Float16* gA1 = A + (size_t)(m0 + 64 + arow) * lda + kcf;
    const _Float16* gB0 = B + (size_t)(n0 + arow) * ldb + kcf;
    const _Float16* gB1 = B + (size_t)(n0 + 64 + arow) * ldb + kcf;
    _Float16* lA0 = As + w * 512;
    _Float16* lA1 = As + 2048 + w * 512;
    _Float16* lB0 = Bs + w * 512;
    _Float16* lB1 = Bs + 2048 + w * 512;

    f32x4 acc[4][4] = {};

    for (int k0 = 0; k0 < K; k0 += 32) {
        __syncthreads();
        lds_load16(gA0 + k0, lA0);
        lds_load16(gA1 + k0, lA1);
        lds_load16(gB0 + k0, lB0);
        lds_load16(gB1 + k0, lB1);
        __syncthreads();

        f16x8 af[4], bf[4];
#pragma unroll
        for (int i = 0; i < 4; ++i)
            af[i] = *(const f16x8*)(As + (wm + i * 16 + ln) * 32 + kq * 8);
#pragma unroll
        for (int i = 0; i < 4; ++i)
            bf[i] = *(const f16x8*)(Bs + (wn + i * 16 + ln) * 32 + kq * 8);
#pragma unroll
        for (int i = 0; i < 4; ++i)
#pragma unroll
            for (int j = 0; j < 4; ++j)
                acc[i][j] = __builtin_amdgcn_mfma_f32_16x16x32_f16(af[i], bf[j], acc[i][j], 0, 0, 0);
    }

    // Epilogue. C/D layout: col = lane&15, row = (lane>>4)*4 + reg.
    const int ldc = (MODE == 0) ? (z == 2 ? 8192 : 1024)
                  : (MODE == 3) ? 2048 : 1024;
    float*    Cf = (float*)Cv;
    _Float16* Ch = (_Float16*)Cv;
#pragma unroll
    for (int i = 0; i < 4; ++i) {
        const int rbase = m0 + wm + i * 16 + kq * 4;

        if (MODE == 0) {
#pragma unroll
            for (int j = 0; j < 4; ++j) {
                const int gcol = n0 + wn + j * 16 + ln;
#pragma unroll
                for (int r = 0; r < 4; ++r) {
                    float vv = acc[i][j][r] + (z == 2 ? bias[rbase + r] : bias[gcol]);
                    Ch[(size_t)(rbase + r) * ldc + gcol] = (_Float16)vv;
                }
            }
        } else if (MODE == 3) {
            float rs[4] = {0.f, 0.f, 0.f, 0.f};
#pragma unroll
            for (int j = 0; j < 4; ++j) {
                const int gcol = n0 + wn + j * 16 + ln;
#pragma unroll
                for (int r = 0; r < 4; ++r) {
                    float e = __expf(acc[i][j][r] * 0.03125f);
                    Ch[cbase + (size_t)(rbase + r) * ldc + gcol] = (_Float16)e;
                    rs[r] += e;
                }
            }
#pragma unroll
            for (int r = 0; r < 4; ++r) {
                float s = rs[r];
                s += __shfl_xor(s, 1);
                s += __shfl_xor(s, 2);
                s += __shfl_xor(s, 4);
                s += __shfl_xor(s, 8);
                if (ln == 0) atomicAdd(&rowsum[rbase + r], s);
            }
        } else { // MODE 5
            float inv[4];
#pragma unroll
            for (int r = 0; r < 4; ++r) inv[r] = 1.f / rowsum[rbase + r];
#pragma unroll
            for (int j = 0; j < 4; ++j) {
                const int gcol = n0 + wn + j * 16 + ln;
#pragma unroll
                for (int r = 0; r < 4; ++r)
                    Cf[cbase + (size_t)(rbase + r) * ldc + gcol] = acc[i][j][r] * inv[r];
            }
        }
    }
}

// ---------------------------------------------------------------------------
// Merged f32->f16 convert for the 3 inputs (grid.y selects);
// y==0, x<32 also zeros rowsum[8192].
// ---------------------------------------------------------------------------
__global__ __launch_bounds__(256)
void cvt_f16(const float4* __restrict__ x0, _Float16* __restrict__ y0,
             const float4* __restrict__ x1, _Float16* __restrict__ y1,
             const float4* __restrict__ x2, _Float16* __restrict__ y2,
             float* __restrict__ rowsum)
{
    const size_t i = (size_t)blockIdx.x * 256 + threadIdx.x;
    const float4* x = blockIdx.y == 0 ? x0 : blockIdx.y == 1 ? x1 : x2;
    _Float16*    yy = blockIdx.y == 0 ? y0 : blockIdx.y == 1 ? y1 : y2;
    float4 f = x[i];
    f16x4 o = { (_Float16)f.x, (_Float16)f.y, (_Float16)f.z, (_Float16)f.w };
    *(f16x4*)(yy + i * 4) = o;
    if (blockIdx.y == 0 && blockIdx.x < 32)
        rowsum[blockIdx.x * 256 + threadIdx.x] = 0.f;
}

// ---------------------------------------------------------------------------
// Merged 1024x1024 f32 -> f16 transpose x3 (grid.z selects W).
// ---------------------------------------------------------------------------
__global__ __launch_bounds__(256)
void transpose_w_1024(const float* __restrict__ W0, _Float16* __restrict__ T0,
                      const float* __restrict__ W1, _Float16* __restrict__ T1,
                      const float* __restrict__ W2, _Float16* __restrict__ T2)
{
    const float* W = blockIdx.z == 0 ? W0 : blockIdx.z == 1 ? W1 : W2;
    _Float16*   WT = blockIdx.z == 0 ? T0 : blockIdx.z == 1 ? T1 : T2;
    __shared__ float tile[32][33];
    const int bx = blockIdx.x * 32;
    const int by = blockIdx.y * 32;
    const int tx = threadIdx.x;
    const int ty = threadIdx.y;
#pragma unroll
    for (int i = ty; i < 32; i += 8)
        tile[i][tx] = W[(size_t)(by + i) * 1024 + bx + tx];
    __syncthreads();
#pragma unroll
    for (int i = ty; i < 32; i += 8)
        WT[(size_t)(bx + i) * 1024 + by + tx] = (_Float16)tile[tx][i];
}

// ---------------------------------------------------------------------------
// B=4, Lq=Lk=2048, D=1024.
// cvt -> transpose -> {q,k,vT} one dispatch -> S~=exp(qk^T/32)+rowsum ->
// out = S~@v / rowsum (plain store).
// ---------------------------------------------------------------------------
extern "C" void kernel_launch(void* const* d_in, const int* in_sizes, int n_in,
                              void* d_out, int out_size, void* d_ws, size_t ws_size,
                              hipStream_t stream)
{
    const float* Xq = (const float*)d_in[0];
    const float* Xk = (const float*)d_in[1];
    const float* Xv = (const float*)d_in[2];
    const float* Wq = (const float*)d_in[3];
    const float* bq = (const float*)d_in[4];
    const float* Wk = (const float*)d_in[5];
    const float* bk = (const float*)d_in[6];
    const float* Wv = (const float*)d_in[7];
    const float* bv = (const float*)d_in[8];
    float* out = (float*)d_out;

    const size_t XN = (size_t)8192 * 1024;
    const size_t WN = (size_t)1024 * 1024;

    _Float16* ws  = (_Float16*)d_ws;
    _Float16* Xqh = ws;
    _Float16* Xkh = Xqh + XN;
    _Float16* Xvh = Xkh + XN;
    _Float16* WqT = Xvh + XN;
    _Float16* WkT = WqT + WN;
    _Float16* WvT = WkT + WN;
    _Float16* qh  = WvT + WN;
    _Float16* kh  = qh + XN;
    _Float16* vT  = kh + XN;                     // [1024 x 8192]
    _Float16* S   = vT + XN;                     // [4 x 2048 x 2048] (holds exp)
    float* rowsum = (float*)(S + (size_t)4 * 2048 * 2048);   // [8192]

    // 1. convert inputs to f16 + zero rowsum
    {
        dim3 g(8192, 3);
        cvt_f16<<<g, 256, 0, stream>>>((const float4*)Xq, Xqh,
                                       (const float4*)Xk, Xkh,
                                       (const float4*)Xv, Xvh, rowsum);
    }

    // 2. transpose weights to f16 W^T (one launch, z=3)
    {
        dim3 tb(32, 8), tg(32, 32, 3);
        transpose_w_1024<<<tg, tb, 0, stream>>>(Wq, WqT, Wk, WkT, Wv, WvT);
    }

    // 3. q, k, vT projections in ONE dispatch (1536 blocks = 6/CU)
    {
        dim3 g(8, 64, 3);
        gemm_core<0><<<g, 256, 0, stream>>>(
            Xqh, WqT, qh, bq,
            Xkh, WkT, kh, bk,
            WvT, Xvh, vT, bv,
            nullptr);
    }

    // 4. S~ = exp(q k^T / 32) f16 + atomic f32 row sums
    {
        dim3 g(16, 16, 4);
        gemm_core<3><<<g, 256, 0, stream>>>(
            qh, kh, S, nullptr,
            nullptr, nullptr, nullptr, nullptr,
            nullptr, nullptr, nullptr, nullptr,
            rowsum);
    }

    // 5. out = (S~ @ v) / rowsum, plain f32 store
    {
        dim3 g(8, 16, 4);
        gemm_core<5><<<g, 256, 0, stream>>>(
            S, vT, out, nullptr,
            nullptr, nullptr, nullptr, nullptr,
            nullptr, nullptr, nullptr, nullptr,
            rowsum);
    }
}

// Round 5
// 333.047 us; speedup vs baseline: 1.1160x; 1.0277x over previous
//
#include <hip/hip_runtime.h>

typedef _Float16 f16x8 __attribute__((ext_vector_type(8)));
typedef _Float16 f16x4 __attribute__((ext_vector_type(4)));
typedef float f32x4 __attribute__((ext_vector_type(4)));

// Async global->LDS, 16B per lane. LDS dest must be wave-uniform base; HW adds lane*16.
__device__ __forceinline__ void lds_load16(const _Float16* g, _Float16* l) {
    __builtin_amdgcn_global_load_lds(
        (const __attribute__((address_space(1))) void*)g,
        (__attribute__((address_space(3))) void*)l,
        16, 0, 0);
}

// ---------------------------------------------------------------------------
// NT GEMM core: C[M,N] = A[M,K]*B[N,K]^T. f16 in, fp32 acc, 128x128 tile,
// BK=32, 256 thr (4 waves, 2x2 of 64x64), mfma_f32_16x16x32_f16,
// global_load_lds width=16, DOUBLE-BUFFERED LDS (1 barrier / K-iter),
// XCD-aware tile swizzle (same A-strip -> same linear_id%8 -> same XCD L2).
//
// MODE 0: triple projection, z in {0,1,2}:
//   z=0: q  = Xq@WqT^T + bq[n]   C[8192,1024] f16, ldc=1024
//   z=1: k  = Xk@WkT^T + bk[n]   C[8192,1024] f16, ldc=1024
//   z=2: vT = WvT@Xv^T + bv[m]   C[1024,8192] f16, ldc=8192 (roles swapped)
// MODE 3: S~ = exp((q k^T)/32) f16 + atomic f32 row sums; z = batch
// MODE 5: out = (S~ @ v) * (1/rowsum[row]) f32 plain store; z = batch
// ---------------------------------------------------------------------------
template <int MODE>
__global__ __launch_bounds__(256, 4)
void gemm_core(const _Float16* A, const _Float16* B, void* Cv, const float* bias,
               const _Float16* Ax1, const _Float16* Bx1, void* Cx1, const float* bx1,
               const _Float16* Ax2, const _Float16* Bx2, void* Cx2, const float* bx2,
               float* rowsum)
{
    const int z = blockIdx.z;
    const int bx = blockIdx.x, by = blockIdx.y;
    size_t cbase = 0;
    int lda, ldb, K, m0, n0;
    if (MODE == 0) {
        // grid (8,64,3); XCD = bx. tmy in [0,64) pins bx -> strip stays on one XCD.
        const int tmy = bx * 8 + (by >> 3);   // 64-tile side
        const int tnx = by & 7;               // 8-tile side
        if (z == 1) { A = Ax1; B = Bx1; Cv = Cx1; bias = bx1; }
        else if (z == 2) { A = Ax2; B = Bx2; Cv = Cx2; bias = bx2; }
        lda = 1024; ldb = 1024; K = 1024;
        m0 = (z == 2 ? tnx : tmy) * 128;
        n0 = (z == 2 ? tmy : tnx) * 128;
    } else if (MODE == 3) {
        // grid (16,16,4); XCD = bx&7.
        const int tm = (bx & 7) * 2 + (by >> 3);
        const int tn = (bx >> 3) * 8 + (by & 7);
        A += (size_t)z * 2048 * 1024;          // q slice
        B += (size_t)z * 2048 * 1024;          // k slice
        cbase = (size_t)z * 2048 * 2048;
        rowsum += z * 2048;
        lda = 1024; ldb = 1024; K = 1024;
        m0 = tm * 128; n0 = tn * 128;
    } else { // MODE 5
        // grid (8,16,4); XCD = bx.
        const int tm = bx * 2 + (by >> 3);
        const int tn = by & 7;
        A += (size_t)z * 2048 * 2048;          // S~ slice
        B += (size_t)z * 2048;                 // vT col offset (ldb 8192)
        cbase = (size_t)z * 2048 * 1024;
        rowsum += z * 2048;
        lda = 2048; ldb = 8192; K = 2048;
        m0 = tm * 128; n0 = tn * 128;
    }

    __shared__ __align__(16) _Float16 As[2][128 * 32];
    __shared__ __align__(16) _Float16 Bs[2][128 * 32];

    const int t    = threadIdx.x;
    const int w    = t >> 6;
    const int lane = t & 63;
    const int ln   = lane & 15;
    const int kq   = lane >> 4;
    const int wm   = (w & 1) * 64;
    const int wn   = (w >> 1) * 64;

    // Staging: 128 rows x 64B per operand. 512 x 16B chunks, 2/thread, LDS contiguous.
    const int arow = t >> 2;
    const int kcf  = (t & 3) * 8;
    const _Float16* gA0 = A + (size_t)(m0 + arow) * lda + kcf;
    const _Float16* gA1 = A + (size_t)(m0 + 64 + arow) * lda + kcf;
    const _Float16* gB0 = B + (size_t)(n0 + arow) * ldb + kcf;
    const _Float16* gB1 = B + (size_t)(n0 + 64 + arow) * ldb + kcf;

    auto stage = [&](int buf, int k0) {
        lds_load16(gA0 + k0, As[buf] + w * 512);
        lds_load16(gA1 + k0, As[buf] + 2048 + w * 512);
        lds_load16(gB0 + k0, Bs[buf] + w * 512);
        lds_load16(gB1 + k0, Bs[buf] + 2048 + w * 512);
    };

    f32x4 acc[4][4] = {};

    stage(0, 0);
    int cur = 0;
#pragma unroll 2
    for (int k0 = 0; k0 < K; k0 += 32) {
        // Drains vmcnt(0): cur-buf loads (issued a full compute phase ago)
        // are ready; also fences prev iter's ds_reads before overwrite.
        __syncthreads();
        if (k0 + 32 < K) stage(cur ^ 1, k0 + 32);   // async into other buf — no barrier

        const _Float16* Ab = As[cur];
        const _Float16* Bb = Bs[cur];
        f16x8 af[4], bf[4];
#pragma unroll
        for (int i = 0; i < 4; ++i)
            af[i] = *(const f16x8*)(Ab + (wm + i * 16 + ln) * 32 + kq * 8);
#pragma unroll
        for (int i = 0; i < 4; ++i)
            bf[i] = *(const f16x8*)(Bb + (wn + i * 16 + ln) * 32 + kq * 8);
#pragma unroll
        for (int i = 0; i < 4; ++i)
#pragma unroll
            for (int j = 0; j < 4; ++j)
                acc[i][j] = __builtin_amdgcn_mfma_f32_16x16x32_f16(af[i], bf[j], acc[i][j], 0, 0, 0);
        cur ^= 1;
    }

    // Epilogue. C/D layout: col = lane&15, row = (lane>>4)*4 + reg.
    const int ldc = (MODE == 0) ? (z == 2 ? 8192 : 1024)
                  : (MODE == 3) ? 2048 : 1024;
    float*    Cf = (float*)Cv;
    _Float16* Ch = (_Float16*)Cv;
#pragma unroll
    for (int i = 0; i < 4; ++i) {
        const int rbase = m0 + wm + i * 16 + kq * 4;

        if (MODE == 0) {
#pragma unroll
            for (int j = 0; j < 4; ++j) {
                const int gcol = n0 + wn + j * 16 + ln;
#pragma unroll
                for (int r = 0; r < 4; ++r) {
                    float vv = acc[i][j][r] + (z == 2 ? bias[rbase + r] : bias[gcol]);
                    Ch[(size_t)(rbase + r) * ldc + gcol] = (_Float16)vv;
                }
            }
        } else if (MODE == 3) {
            float rs[4] = {0.f, 0.f, 0.f, 0.f};
#pragma unroll
            for (int j = 0; j < 4; ++j) {
                const int gcol = n0 + wn + j * 16 + ln;
#pragma unroll
                for (int r = 0; r < 4; ++r) {
                    float e = __expf(acc[i][j][r] * 0.03125f);
                    Ch[cbase + (size_t)(rbase + r) * ldc + gcol] = (_Float16)e;
                    rs[r] += e;
                }
            }
#pragma unroll
            for (int r = 0; r < 4; ++r) {
                float s = rs[r];
                s += __shfl_xor(s, 1);
                s += __shfl_xor(s, 2);
                s += __shfl_xor(s, 4);
                s += __shfl_xor(s, 8);
                if (ln == 0) atomicAdd(&rowsum[rbase + r], s);
            }
        } else { // MODE 5
            float inv[4];
#pragma unroll
            for (int r = 0; r < 4; ++r) inv[r] = 1.f / rowsum[rbase + r];
#pragma unroll
            for (int j = 0; j < 4; ++j) {
                const int gcol = n0 + wn + j * 16 + ln;
#pragma unroll
                for (int r = 0; r < 4; ++r)
                    Cf[cbase + (size_t)(rbase + r) * ldc + gcol] = acc[i][j][r] * inv[r];
            }
        }
    }
}

// ---------------------------------------------------------------------------
// Merged f32->f16 convert for the 3 inputs (grid.y selects);
// y==0, x<32 also zeros rowsum[8192].
// ---------------------------------------------------------------------------
__global__ __launch_bounds__(256)
void cvt_f16(const float4* __restrict__ x0, _Float16* __restrict__ y0,
             const float4* __restrict__ x1, _Float16* __restrict__ y1,
             const float4* __restrict__ x2, _Float16* __restrict__ y2,
             float* __restrict__ rowsum)
{
    const size_t i = (size_t)blockIdx.x * 256 + threadIdx.x;
    const float4* x = blockIdx.y == 0 ? x0 : blockIdx.y == 1 ? x1 : x2;
    _Float16*    yy = blockIdx.y == 0 ? y0 : blockIdx.y == 1 ? y1 : y2;
    float4 f = x[i];
    f16x4 o = { (_Float16)f.x, (_Float16)f.y, (_Float16)f.z, (_Float16)f.w };
    *(f16x4*)(yy + i * 4) = o;
    if (blockIdx.y == 0 && blockIdx.x < 32)
        rowsum[blockIdx.x * 256 + threadIdx.x] = 0.f;
}

// ---------------------------------------------------------------------------
// Merged 1024x1024 f32 -> f16 transpose x3 (grid.z selects W).
// ---------------------------------------------------------------------------
__global__ __launch_bounds__(256)
void transpose_w_1024(const float* __restrict__ W0, _Float16* __restrict__ T0,
                      const float* __restrict__ W1, _Float16* __restrict__ T1,
                      const float* __restrict__ W2, _Float16* __restrict__ T2)
{
    const float* W = blockIdx.z == 0 ? W0 : blockIdx.z == 1 ? W1 : W2;
    _Float16*   WT = blockIdx.z == 0 ? T0 : blockIdx.z == 1 ? T1 : T2;
    __shared__ float tile[32][33];
    const int bx = blockIdx.x * 32;
    const int by = blockIdx.y * 32;
    const int tx = threadIdx.x;
    const int ty = threadIdx.y;
#pragma unroll
    for (int i = ty; i < 32; i += 8)
        tile[i][tx] = W[(size_t)(by + i) * 1024 + bx + tx];
    __syncthreads();
#pragma unroll
    for (int i = ty; i < 32; i += 8)
        WT[(size_t)(bx + i) * 1024 + by + tx] = (_Float16)tile[tx][i];
}

// ---------------------------------------------------------------------------
// B=4, Lq=Lk=2048, D=1024.
// cvt -> transpose -> {q,k,vT} one dispatch -> S~=exp(qk^T/32)+rowsum ->
// out = S~@v / rowsum (plain store).
// ---------------------------------------------------------------------------
extern "C" void kernel_launch(void* const* d_in, const int* in_sizes, int n_in,
                              void* d_out, int out_size, void* d_ws, size_t ws_size,
                              hipStream_t stream)
{
    const float* Xq = (const float*)d_in[0];
    const float* Xk = (const float*)d_in[1];
    const float* Xv = (const float*)d_in[2];
    const float* Wq = (const float*)d_in[3];
    const float* bq = (const float*)d_in[4];
    const float* Wk = (const float*)d_in[5];
    const float* bk = (const float*)d_in[6];
    const float* Wv = (const float*)d_in[7];
    const float* bv = (const float*)d_in[8];
    float* out = (float*)d_out;

    const size_t XN = (size_t)8192 * 1024;
    const size_t WN = (size_t)1024 * 1024;

    _Float16* ws  = (_Float16*)d_ws;
    _Float16* Xqh = ws;
    _Float16* Xkh = Xqh + XN;
    _Float16* Xvh = Xkh + XN;
    _Float16* WqT = Xvh + XN;
    _Float16* WkT = WqT + WN;
    _Float16* WvT = WkT + WN;
    _Float16* qh  = WvT + WN;
    _Float16* kh  = qh + XN;
    _Float16* vT  = kh + XN;                     // [1024 x 8192]
    _Float16* S   = vT + XN;                     // [4 x 2048 x 2048] (holds exp)
    float* rowsum = (float*)(S + (size_t)4 * 2048 * 2048);   // [8192]

    // 1. convert inputs to f16 + zero rowsum
    {
        dim3 g(8192, 3);
        cvt_f16<<<g, 256, 0, stream>>>((const float4*)Xq, Xqh,
                                       (const float4*)Xk, Xkh,
                                       (const float4*)Xv, Xvh, rowsum);
    }

    // 2. transpose weights to f16 W^T (one launch, z=3)
    {
        dim3 tb(32, 8), tg(32, 32, 3);
        transpose_w_1024<<<tg, tb, 0, stream>>>(Wq, WqT, Wk, WkT, Wv, WvT);
    }

    // 3. q, k, vT projections in ONE dispatch (1536 blocks = 6/CU)
    {
        dim3 g(8, 64, 3);
        gemm_core<0><<<g, 256, 0, stream>>>(
            Xqh, WqT, qh, bq,
            Xkh, WkT, kh, bk,
            WvT, Xvh, vT, bv,
            nullptr);
    }

    // 4. S~ = exp(q k^T / 32) f16 + atomic f32 row sums
    {
        dim3 g(16, 16, 4);
        gemm_core<3><<<g, 256, 0, stream>>>(
            qh, kh, S, nullptr,
            nullptr, nullptr, nullptr, nullptr,
            nullptr, nullptr, nullptr, nullptr,
            rowsum);
    }

    // 5. out = (S~ @ v) / rowsum, plain f32 store
    {
        dim3 g(8, 16, 4);
        gemm_core<5><<<g, 256, 0, stream>>>(
            S, vT, out, nullptr,
            nullptr, nullptr, nullptr, nullptr,
            nullptr, nullptr, nullptr, nullptr,
            rowsum);
    }
}